// Round 8
// baseline (172.364 us; speedup 1.0000x reference)
//
#include <hip/hip_runtime.h>

#define NB 512
#define NN 256
#define EPG 8192
#define FINC 128

typedef float f32x4 __attribute__((ext_vector_type(4)));
typedef short s16x8 __attribute__((ext_vector_type(8)));

__device__ __forceinline__ float bf2f(unsigned short u) {
  union { unsigned int i; float f; } x; x.i = ((unsigned int)u) << 16; return x.f;
}
__device__ __forceinline__ unsigned short f2bf(float f) {
  union { float f; unsigned int i; } x; x.f = f;
  unsigned int r = x.i + 0x7fffu + ((x.i >> 16) & 1u);
  return (unsigned short)(r >> 16);
}
__device__ __forceinline__ unsigned pk2(unsigned short a, unsigned short c) {
  return (unsigned)a | ((unsigned)c << 16);
}

// decode 8 adjacency nibbles of d -> bf16(16 + n) fragments.
// bf16(16+n) = 0x4180 | (n<<3), exact for n in [0,15].
// consumers must subtract 16*colsum(B) from the MFMA result.
union U16x8 { uint4 u; s16x8 s; };
__device__ __forceinline__ s16x8 dec8(unsigned d) {
  U16x8 o;
  o.u.x = 0x41804180u | ((d & 0x0000000Fu) << 3)  | ((d & 0x000000F0u) << 15);
  o.u.y = 0x41804180u | ((d & 0x00000F00u) >> 5)  | ((d & 0x0000F000u) << 7);
  o.u.z = 0x41804180u | ((d & 0x000F0000u) >> 13) | ((d & 0x00F00000u) >> 1);
  o.u.w = 0x41804180u | ((d & 0x0F000000u) >> 21) | ((d & 0xF0000000u) >> 9);
  return o.s;
}

struct Params {
  const void* x; const void* ei;
  const void *wl1, *bl1, *wr1, *br1, *wro1, *wp, *bp;
  const void *wr2, *br2, *wro2, *wl2, *bl2, *wl3, *bl3;
  float* out; float* ws;
};

__device__ __forceinline__ float ldf(const void* p, int i, bool bf) {
  return bf ? bf2f(((const unsigned short*)p)[i]) : ((const float*)p)[i];
}

// ---- LDS (81920 B total => 2 blocks/CU) ----
// Same map as R7. 512 threads now; each wave owns row-groups wv and wv+8.
#define SMEM_TOTAL 81920

__global__ __launch_bounds__(512, 4) void mincut_main(Params P) {
  extern __shared__ char smem[];
  const int t = threadIdx.x;
  const int b = blockIdx.x;

  const int wv = t >> 6, lane = t & 63;
  const int lm = lane & 15, quad = lane >> 4;

  // ---- Bf: PARALLEL dtype detection (one load per lane, ballot reduce) ----
  int* flg = (int*)(smem + 78656);
  if (wv == 0) {
    const unsigned short* pw = (const unsigned short*)P.wr1;
    unsigned e = (pw[lane] >> 7) & 0xFFu;
    unsigned long long m = __ballot(e > 96u && e < 132u);
    if (lane == 0) flg[0] = (__popcll(m) >= 56) ? 1 : 0;
  } else if (wv == 1) {
    const int* pi = (const int*)P.ei + EPG;
    bool c = false;
    if (lane < 32) { int v = pi[lane]; c = (v >= 256 && v < 512); }
    unsigned long long m = __ballot(c);
    if (lane == 0) flg[1] = (__popcll(m) < 24) ? 1 : 0;
  }

  // A tail
  float* oadjb  = (float*)(smem + 2048);
  float* ddb    = (float*)(smem + 6144);
  float* caf    = (float*)(smem + 6208);
  float* psf    = (float*)(smem + 6272);
  float* qsf    = (float*)(smem + 6400);
  float* rb     = (float*)(smem + 8256);
  float* yb     = (float*)(smem + 8384);
  float* lgb    = (float*)(smem + 8512);
  float* rel2f  = (float*)(smem + 9216);
  float* root2f = (float*)(smem + 13312);
  float* lin2f  = (float*)(smem + 17408);
  float* lin3f  = (float*)(smem + 21504);
  float* brel2f = (float*)(smem + 22784);
  float* blin2f = (float*)(smem + 22912);
  float* blin3f = (float*)(smem + 23040);
  float* pbuf   = (float*)(smem + 24576);
  float* ssA    = (float*)(smem + 30720);
  // B
  unsigned short* h0T  = (unsigned short*)(smem + 33792);
  unsigned short* h1Th = (unsigned short*)(smem + 33792);
  // C
  unsigned short* w1t  = (unsigned short*)(smem + 50688);
  unsigned short* zT   = (unsigned short*)(smem + 50688);
  unsigned short* sTh  = (unsigned short*)(smem + 50688);
  // D
  unsigned short* wrelTh = (unsigned short*)(smem + 67584);
  unsigned short* wrootT = (unsigned short*)(smem + 72704);
  float* blin1f = (float*)(smem + 75264);   // 32 f (dead after P1)
  unsigned short* taT = (unsigned short*)(smem + 67584);
  // E
  unsigned short* wpoolTh = (unsigned short*)(smem + 76032); // [16][36]
  float*          colzF   = (float*)(smem + 78336);          // [32]
  float*          colsF   = (float*)(smem + 78464);          // [16]
  float*          scrE    = (float*)(smem + 78528);          // [16] den scratch
  float*          bpf     = (float*)(smem + 78592);          // [16]
  unsigned short* brel1h  = (unsigned short*)(smem + 81856); // 32 bf16

  // ---- zero adj (u4) + corr bufs (LDS only) ----
  {
    uint4 z = {0u, 0u, 0u, 0u};
    for (int i = t; i < 2112; i += 512) ((uint4*)smem)[i] = z;
  }
  if (t < 48) colzF[t] = 0.f;   // colzF[32] + colsF[16], contiguous
  __syncthreads();   // B0a: adj zeroed, flags ready

  const bool BF  = (flg[0] != 0);
  const bool I64 = (flg[1] != 0);

  // ---- overlapped front window: edge loads -> weight staging -> atomics -> x preload ----
  // 1) issue ALL edge loads into registers FIRST (16 edges/thread)
  uint4 ea[8], eb[8];
  if (I64) {
    const uint4* s4 = (const uint4*)((const long long*)P.ei + (size_t)b * EPG) + t * 8;
    const uint4* d4 = (const uint4*)((const long long*)P.ei + (size_t)NB * EPG + (size_t)b * EPG) + t * 8;
    #pragma unroll
    for (int i = 0; i < 8; ++i) { ea[i] = s4[i]; eb[i] = d4[i]; }
  } else {
    const uint4* s4 = (const uint4*)((const int*)P.ei + (size_t)b * EPG) + t * 4;
    const uint4* d4 = (const uint4*)((const int*)P.ei + (size_t)NB * EPG + (size_t)b * EPG) + t * 4;
    #pragma unroll
    for (int i = 0; i < 4; ++i) { ea[i] = s4[i]; eb[i] = d4[i]; }
  }

  // 2) weight staging (global-load latency overlaps the edge loads above)
  for (int e = t; e < 4096; e += 512) {
    int k = e >> 5, c = e & 31;
    w1t[c * 136 + k] = f2bf(ldf(P.wl1, e, BF));
  }
  for (int i = t; i < 1024; i += 512) {
    int k = i >> 5, c = i & 31;
    wrelTh[c * 40 + k] = f2bf(ldf(P.wr1, i, BF));
    wrootT[c * 40 + k] = f2bf(ldf(P.wro1, i, BF));
  }
  {
    int m = t >> 4, c = t & 15;
    wpoolTh[c * 36 + m] = f2bf(ldf(P.wp, t, BF));
  }
  if (t < 32) { blin1f[t] = ldf(P.bl1, t, BF); brel1h[t] = f2bf(ldf(P.br1, t, BF)); }
  if (t < 16) bpf[t] = ldf(P.bp, t, BF);

  // 3) adjacency nibble atomics (consume edge regs; LDS only)
  if (I64) {
    #pragma unroll
    for (int i = 0; i < 8; ++i) {
      unsigned n0 = (ea[i].x & 255u) * 264u + (eb[i].x & 255u);
      unsigned n1 = (ea[i].z & 255u) * 264u + (eb[i].z & 255u);
      atomicAdd((unsigned int*)(smem + ((n0 >> 3) << 2)), 1u << ((n0 & 7u) * 4u));
      atomicAdd((unsigned int*)(smem + ((n1 >> 3) << 2)), 1u << ((n1 & 7u) * 4u));
    }
  } else {
    #pragma unroll
    for (int i = 0; i < 4; ++i) {
      unsigned n0 = (ea[i].x & 255u) * 264u + (eb[i].x & 255u);
      unsigned n1 = (ea[i].y & 255u) * 264u + (eb[i].y & 255u);
      unsigned n2 = (ea[i].z & 255u) * 264u + (eb[i].z & 255u);
      unsigned n3 = (ea[i].w & 255u) * 264u + (eb[i].w & 255u);
      atomicAdd((unsigned int*)(smem + ((n0 >> 3) << 2)), 1u << ((n0 & 7u) * 4u));
      atomicAdd((unsigned int*)(smem + ((n1 >> 3) << 2)), 1u << ((n1 & 7u) * 4u));
      atomicAdd((unsigned int*)(smem + ((n2 >> 3) << 2)), 1u << ((n2 & 7u) * 4u));
      atomicAdd((unsigned int*)(smem + ((n3 >> 3) << 2)), 1u << ((n3 & 7u) * 4u));
    }
  }

  // 4) x preload into registers for both row-groups
  s16x8 xa[2][4];
  #pragma unroll
  for (int g = 0; g < 2; ++g) {
    const int mbase = (wv + g * 8) * 16;
    const size_t node = (size_t)(b * 256 + mbase + lm);
    if (BF) {
      #pragma unroll
      for (int ks = 0; ks < 4; ++ks)
        xa[g][ks] = *(const s16x8*)((const unsigned short*)P.x + node * 128 + ks * 32 + quad * 8);
    } else {
      #pragma unroll
      for (int ks = 0; ks < 4; ++ks) {
        const float* xp = (const float*)P.x + node * 128 + ks * 32 + quad * 8;
        f32x4 v0 = *(const f32x4*)xp;
        f32x4 v1 = *(const f32x4*)(xp + 4);
        #pragma unroll
        for (int j = 0; j < 4; ++j) { xa[g][ks][j] = (short)f2bf(v0[j]); xa[g][ks][4 + j] = (short)f2bf(v1[j]); }
      }
    }
  }
  __syncthreads();   // B0b: adj counts + staged weights ready

  // ---- P1: h0 = x @ W1 + b (two independent row-groups per wave) ----
  {
    f32x4 acc[2][2] = {{{0.f,0.f,0.f,0.f},{0.f,0.f,0.f,0.f}},
                       {{0.f,0.f,0.f,0.f},{0.f,0.f,0.f,0.f}}};
    #pragma unroll
    for (int ks = 0; ks < 4; ++ks) {
      const int k0 = ks * 32 + quad * 8;
      #pragma unroll
      for (int ct = 0; ct < 2; ++ct) {
        s16x8 bh = *(const s16x8*)(w1t + (ct * 16 + lm) * 136 + k0);
        acc[0][ct] = __builtin_amdgcn_mfma_f32_16x16x32_bf16(xa[0][ks], bh, acc[0][ct], 0, 0, 0);
        acc[1][ct] = __builtin_amdgcn_mfma_f32_16x16x32_bf16(xa[1][ks], bh, acc[1][ct], 0, 0, 0);
      }
    }
    #pragma unroll
    for (int g = 0; g < 2; ++g) {
      const int mbase = (wv + g * 8) * 16;
      #pragma unroll
      for (int ct = 0; ct < 2; ++ct) {
        const int c = ct * 16 + lm;
        float bias = blin1f[c];
        *(uint2*)(h0T + c * 264 + mbase + quad * 4) =
            make_uint2(pk2(f2bf(acc[g][ct][0] + bias), f2bf(acc[g][ct][1] + bias)),
                       pk2(f2bf(acc[g][ct][2] + bias), f2bf(acc[g][ct][3] + bias)));
      }
    }
  }
  __syncthreads();   // B1: h0T ready

  // ---- Pz1: z = h0@Wrel, r = h0@Wroot (both groups); zT + colz atomics ----
  f32x4 racc[2][2] = {{{0.f,0.f,0.f,0.f},{0.f,0.f,0.f,0.f}},
                      {{0.f,0.f,0.f,0.f},{0.f,0.f,0.f,0.f}}};
  {
    s16x8 Ah[2];
    #pragma unroll
    for (int g = 0; g < 2; ++g) {
      const int mbase = (wv + g * 8) * 16;
      #pragma unroll
      for (int j = 0; j < 8; ++j) Ah[g][j] = (short)h0T[(quad * 8 + j) * 264 + mbase + lm];
    }
    f32x4 zacc[2][2] = {{{0.f,0.f,0.f,0.f},{0.f,0.f,0.f,0.f}},
                        {{0.f,0.f,0.f,0.f},{0.f,0.f,0.f,0.f}}};
    #pragma unroll
    for (int ct = 0; ct < 2; ++ct) {
      const int c = ct * 16 + lm;
      s16x8 brh = *(const s16x8*)(wrelTh + c * 40 + quad * 8);
      s16x8 bro = *(const s16x8*)(wrootT + c * 40 + quad * 8);
      #pragma unroll
      for (int g = 0; g < 2; ++g) {
        zacc[g][ct] = __builtin_amdgcn_mfma_f32_16x16x32_bf16(Ah[g], brh, zacc[g][ct], 0, 0, 0);
        racc[g][ct] = __builtin_amdgcn_mfma_f32_16x16x32_bf16(Ah[g], bro, racc[g][ct], 0, 0, 0);
      }
    }
    #pragma unroll
    for (int g = 0; g < 2; ++g) {
      const int mbase = (wv + g * 8) * 16;
      #pragma unroll
      for (int ct = 0; ct < 2; ++ct) {
        unsigned short u0 = f2bf(zacc[g][ct][0]), u1 = f2bf(zacc[g][ct][1]);
        unsigned short u2 = f2bf(zacc[g][ct][2]), u3 = f2bf(zacc[g][ct][3]);
        *(uint2*)(zT + (ct * 16 + lm) * 264 + mbase + quad * 4) =
            make_uint2(pk2(u0, u1), pk2(u2, u3));
        float pz = (bf2f(u0) + bf2f(u1)) + (bf2f(u2) + bf2f(u3));
        pz += __shfl_xor(pz, 16, 64);
        pz += __shfl_xor(pz, 32, 64);
        if (lane < 16) atomicAdd(colzF + ct * 16 + lm, pz);
      }
    }
  }
  __syncthreads();   // B2: wrelT/wrootT/h0T reads done; colzF complete

  // ---- 4a: h1 = A@z + r + brel - 16*colz (both groups); deg; write h1Th ----
  float degf[2];
  {
    #pragma unroll
    for (int g = 0; g < 2; ++g) {
      const int mbase = (wv + g * 8) * 16;
      f32x4 h1acc[2] = { racc[g][0], racc[g][1] };
      unsigned dsum = 0;
      const char* arow = smem + (mbase + lm) * 132;
      #pragma unroll
      for (int ks = 0; ks < 8; ++ks) {
        unsigned d = *(const unsigned int*)(arow + ks * 16 + quad * 4);
        unsigned v = (d & 0x0F0F0F0Fu) + ((d >> 4) & 0x0F0F0F0Fu);
        dsum += (v * 0x01010101u) >> 24;
        s16x8 af = dec8(d);
        const int v0 = ks * 32 + quad * 8;
        #pragma unroll
        for (int ct = 0; ct < 2; ++ct) {
          s16x8 bz = *(const s16x8*)(zT + (ct * 16 + lm) * 264 + v0);
          h1acc[ct] = __builtin_amdgcn_mfma_f32_16x16x32_bf16(af, bz, h1acc[ct], 0, 0, 0);
        }
      }
      dsum += __shfl_xor(dsum, 16, 64);
      dsum += __shfl_xor(dsum, 32, 64);
      degf[g] = (float)dsum;   // deg of node mbase+lm
      #pragma unroll
      for (int ct = 0; ct < 2; ++ct) {
        const int c = ct * 16 + lm;
        float bias = bf2f(brel1h[c]) - 16.f * colzF[c];   // offset-16 correction
        *(uint2*)(h1Th + c * 264 + mbase + quad * 4) =
            make_uint2(pk2(f2bf(h1acc[ct][0] + bias), f2bf(h1acc[ct][1] + bias)),
                       pk2(f2bf(h1acc[ct][2] + bias), f2bf(h1acc[ct][3] + bias)));
      }
    }
  }
  __syncthreads();   // B4: h1Th ready; zT reads done

  // ---- 4c: s2 = h1@Wpool + bp ; softmax ; sTh ; den partial (both groups) ----
  {
    s16x8 Bh;
    ((uint2*)&Bh)[0] = *(const uint2*)(wpoolTh + lm * 36 + quad * 8);
    ((uint2*)&Bh)[1] = *(const uint2*)(wpoolTh + lm * 36 + quad * 8 + 4);
    #pragma unroll
    for (int g = 0; g < 2; ++g) {
      const int mbase = (wv + g * 8) * 16;
      s16x8 Ah1;
      #pragma unroll
      for (int j = 0; j < 8; ++j) Ah1[j] = (short)h1Th[(quad * 8 + j) * 264 + mbase + lm];
      f32x4 lacc = {0.f, 0.f, 0.f, 0.f};
      lacc = __builtin_amdgcn_mfma_f32_16x16x32_bf16(Ah1, Bh, lacc, 0, 0, 0);
      f32x4 lg;
      float bm = bpf[lm];
      #pragma unroll
      for (int r = 0; r < 4; ++r) lg[r] = lacc[r] + bm;
      f32x4 mx = lg;
      #pragma unroll
      for (int m = 1; m <= 8; m <<= 1)
        #pragma unroll
        for (int r = 0; r < 4; ++r) mx[r] = fmaxf(mx[r], __shfl_xor(mx[r], m, 64));
      #pragma unroll
      for (int r = 0; r < 4; ++r) lg[r] = __expf(lg[r] - mx[r]);
      f32x4 sm = lg;
      #pragma unroll
      for (int m = 1; m <= 8; m <<= 1)
        #pragma unroll
        for (int r = 0; r < 4; ++r) sm[r] += __shfl_xor(sm[r], m, 64);
      f32x4 sval, sq;
      #pragma unroll
      for (int r = 0; r < 4; ++r) { sval[r] = lg[r] / sm[r]; sq[r] = sval[r] * sval[r]; }
      #pragma unroll
      for (int m = 1; m <= 8; m <<= 1)
        #pragma unroll
        for (int r = 0; r < 4; ++r) sq[r] += __shfl_xor(sq[r], m, 64);
      // sTh packed writes + cols atomics
      {
        unsigned short h0s = f2bf(sval[0]);
        unsigned short h1s = f2bf(sval[1]);
        unsigned short h2s = f2bf(sval[2]);
        unsigned short h3s = f2bf(sval[3]);
        const int nb = lm * 264 + mbase + quad * 4;
        *(uint2*)(sTh + nb) = make_uint2(pk2(h0s, h1s), pk2(h2s, h3s));
        float sr = (bf2f(h0s) + bf2f(h1s)) + (bf2f(h2s) + bf2f(h3s));
        sr += __shfl_xor(sr, 16, 64);
        sr += __shfl_xor(sr, 32, 64);
        if (lane < 16) atomicAdd(colsF + lm, sr);
      }
      // den partial: node mbase+l (l<16): ssq from quad l>>2, slot l&3
      {
        int l = lane & 15, src = (l >> 2) << 4;
        float q0 = __shfl(sq[0], src, 64), q1 = __shfl(sq[1], src, 64);
        float q2 = __shfl(sq[2], src, 64), q3 = __shfl(sq[3], src, 64);
        float ssel = (l & 2) ? ((l & 1) ? q3 : q2) : ((l & 1) ? q1 : q0);
        float vden = (lane < 16) ? degf[g] * ssel : 0.f;
        #pragma unroll
        for (int o = 32; o > 0; o >>= 1) vden += __shfl_xor(vden, o, 64);
        if (lane == 0) scrE[g * 8 + wv] = vden;
      }
    }
  }
  __syncthreads();   // B5: sTh ready; colsF complete

  // ---- P5: tA = A@s -> taT bf16 (both groups) ----
  {
    float cols = colsF[lm];
    float c16 = 16.f * cols;                            // offset-16 correction
    #pragma unroll
    for (int g = 0; g < 2; ++g) {
      const int mbase = (wv + g * 8) * 16;
      f32x4 tacc = {0.f, 0.f, 0.f, 0.f};
      const char* arow = smem + (mbase + lm) * 132;
      #pragma unroll
      for (int ks = 0; ks < 8; ++ks) {
        unsigned d = *(const unsigned int*)(arow + ks * 16 + quad * 4);
        s16x8 af = dec8(d);
        const int v0 = ks * 32 + quad * 8;
        s16x8 bh = *(const s16x8*)(sTh + lm * 264 + v0);
        tacc = __builtin_amdgcn_mfma_f32_16x16x32_bf16(af, bh, tacc, 0, 0, 0);
      }
      *(uint2*)(taT + lm * 264 + mbase + quad * 4) =
          make_uint2(pk2(f2bf(tacc[0] - c16), f2bf(tacc[1] - c16)),
                     pk2(f2bf(tacc[2] - c16), f2bf(tacc[3] - c16)));
    }
  }
  __syncthreads();   // B6: adjacency dead

  // ---- P6: FG weights global -> A tail + 4 MFMA reduction jobs ----
  for (int i = t; i < 1024; i += 512) {
    rel2f[i] = ldf(P.wr2, i, BF);
    root2f[i] = ldf(P.wro2, i, BF);
    lin2f[i] = ldf(P.wl2, i, BF);
  }
  if (t < 320) lin3f[t] = ldf(P.wl3, t, BF);
  if (t < 32) brel2f[t] = ldf(P.br2, t, BF);
  if (t < 32) blin2f[t] = ldf(P.bl2, t, BF);
  if (t < 10) blin3f[t] = ldf(P.bl3, t, BF);

  if (wv < 4) {
    const unsigned short* Ap = sTh;
    const unsigned short* Bp; float* dst; int W, ct = 0;
    switch (wv) {
      case 0: Bp = h1Th; dst = pbuf;  W = 32; ct = 0; break;
      case 1: Bp = h1Th; dst = pbuf;  W = 32; ct = 1; break;
      case 2: Bp = taT;  dst = oadjb; W = 16; break;
      default: Bp = sTh; dst = ssA;   W = 16; break;
    }
    const int cidx = ct * 16 + lm;
    const unsigned short* Bb = Bp + cidx * 264;
    f32x4 acc = {0.f, 0.f, 0.f, 0.f};
    #pragma unroll
    for (int ch = 0; ch < 8; ++ch) {
      s16x8 a = *(const s16x8*)(Ap + lm * 264 + ch * 32 + quad * 8);
      s16x8 bb = *(const s16x8*)(Bb + ch * 32 + quad * 8);
      acc = __builtin_amdgcn_mfma_f32_16x16x32_bf16(a, bb, acc, 0, 0, 0);
    }
    #pragma unroll
    for (int r = 0; r < 4; ++r) dst[(quad * 4 + r) * W + cidx] = acc[r];
  }
  __syncthreads();   // B7 — LAST barrier

  // ---- tail: wave0 = output chain (intra-wave), wave1 = loss chain ----
  if (wv == 0) {
    // degree vector of pooled adj (row sums excluding diag)
    if (lane < 16) {
      float rs = 0.f;
      #pragma unroll
      for (int j = 0; j < 16; ++j) if (j != lane) rs += oadjb[lane * 16 + j];
      ddb[lane] = sqrtf(rs) + 1e-15f;
    }
    // colsums of normalized adj (never materialize the matrix)
    if (lane < 16) {
      float s = 0.f;
      float dj = ddb[lane];
      #pragma unroll
      for (int k = 0; k < 16; ++k)
        if (k != lane) s += oadjb[k * 16 + lane] / (ddb[k] * dj);
      caf[lane] = s;
    }
    // ps = colsum(pbuf), qs = ca^T pbuf   (readout-sum commuted past conv2)
    if (lane < 32) {
      float ps = 0.f, qs = 0.f;
      #pragma unroll
      for (int j = 0; j < 16; ++j) {
        float pv = pbuf[j * 32 + lane];
        ps += pv;
        qs += caf[j] * pv;
      }
      psf[lane] = ps; qsf[lane] = qs;
    }
    // r = 16*brel2 + qs@Wrel2 + ps@Wroot2
    if (lane < 32) {
      float r = 16.f * brel2f[lane];
      #pragma unroll
      for (int m = 0; m < 32; ++m)
        r += qsf[m] * rel2f[m * 32 + lane] + psf[m] * root2f[m * 32 + lane];
      rb[lane] = r;
    }
    if (lane < 32) {
      float y = blin2f[lane];
      #pragma unroll
      for (int m = 0; m < 32; ++m) y += rb[m] * lin2f[m * 32 + lane];
      yb[lane] = fmaxf(y, 0.f);
    }
    if (lane < 10) {
      float lg = blin3f[lane];
      #pragma unroll
      for (int m = 0; m < 32; ++m) lg += yb[m] * lin3f[m * 10 + lane];
      lgb[lane] = lg;
    }
    if (lane == 0) {
      float mx = lgb[0];
      #pragma unroll
      for (int i = 1; i < 10; ++i) mx = fmaxf(mx, lgb[i]);
      float sum = 0.f;
      #pragma unroll
      for (int i = 0; i < 10; ++i) sum += __expf(lgb[i] - mx);
      lgb[10] = mx + __logf(sum);
    }
    if (lane < 10) {
      float val = lgb[lane] - lgb[10];
      if (BF) ((unsigned short*)P.out)[b * 10 + lane] = f2bf(val);
      else    P.out[b * 10 + lane] = val;
    }
  } else if (wv == 1) {
    float vfro = 0.f, vtr = 0.f;
    #pragma unroll
    for (int u = 0; u < 4; ++u) {
      int i = lane * 4 + u, k = i >> 4, j = i & 15;
      float ssv = ssA[i];
      vfro += ssv * ssv;
      if (k == j) vtr += ssv;
    }
    float vnum = (lane < 16) ? oadjb[lane * 17] : 0.f;
    float vden = (lane < 16) ? scrE[lane] : 0.f;
    #pragma unroll
    for (int o = 32; o > 0; o >>= 1) {
      vfro += __shfl_xor(vfro, o, 64);
      vtr  += __shfl_xor(vtr, o, 64);
      vnum += __shfl_xor(vnum, o, 64);
      vden += __shfl_xor(vden, o, 64);
    }
    if (lane == 0) {
      float ssn = sqrtf(vfro);
      float orth2 = 2.f - vtr / (2.f * ssn);
      atomicAdd(P.ws, -(vnum / vden) * (1.f / NB));
      atomicAdd(P.ws + 1, sqrtf(fmaxf(orth2, 0.f)) * (1.f / NB));
      // completion counter: last block writes the loss outputs (folds mincut_fin)
      __threadfence();
      unsigned old = atomicAdd((unsigned int*)(P.ws + 2), 1u);
      if (old == (unsigned)(NB - 1)) {
        float l0 = atomicAdd(P.ws, 0.f);      // coherent RMW reads
        float l1 = atomicAdd(P.ws + 1, 0.f);
        if (BF) {
          ((unsigned short*)P.out)[5120] = f2bf(l0);
          ((unsigned short*)P.out)[5121] = f2bf(l1);
        } else {
          P.out[5120] = l0;
          P.out[5121] = l1;
        }
      }
    }
  }
}

extern "C" void kernel_launch(void* const* d_in, const int* in_sizes, int n_in,
                              void* d_out, int out_size, void* d_ws, size_t ws_size,
                              hipStream_t stream) {
  (void)in_sizes; (void)n_in; (void)out_size; (void)ws_size;
  Params P;
  P.x    = d_in[0];
  P.ei   = d_in[1];
  P.wl1  = d_in[3];
  P.bl1  = d_in[4];
  P.wr1  = d_in[5];
  P.br1  = d_in[6];
  P.wro1 = d_in[7];
  P.wp   = d_in[8];
  P.bp   = d_in[9];
  P.wr2  = d_in[10];
  P.br2  = d_in[11];
  P.wro2 = d_in[12];
  P.wl2  = d_in[13];
  P.bl2  = d_in[14];
  P.wl3  = d_in[15];
  P.bl3  = d_in[16];
  P.out  = (float*)d_out;
  P.ws   = (float*)d_ws;

  hipMemsetAsync(d_ws, 0, 4 * sizeof(float), stream);
  hipFuncSetAttribute(reinterpret_cast<const void*>(mincut_main),
                      hipFuncAttributeMaxDynamicSharedMemorySize, SMEM_TOTAL);
  hipLaunchKernelGGL(mincut_main, dim3(NB), dim3(512), SMEM_TOTAL, stream, P);
}

// Round 9
// 166.190 us; speedup vs baseline: 1.0371x; 1.0371x over previous
//
#include <hip/hip_runtime.h>

#define NB 512
#define NN 256
#define EPG 8192
#define FINC 128

typedef float f32x4 __attribute__((ext_vector_type(4)));
typedef short s16x8 __attribute__((ext_vector_type(8)));

__device__ __forceinline__ float bf2f(unsigned short u) {
  union { unsigned int i; float f; } x; x.i = ((unsigned int)u) << 16; return x.f;
}
__device__ __forceinline__ unsigned short f2bf(float f) {
  union { float f; unsigned int i; } x; x.f = f;
  unsigned int r = x.i + 0x7fffu + ((x.i >> 16) & 1u);
  return (unsigned short)(r >> 16);
}
__device__ __forceinline__ unsigned pk2(unsigned short a, unsigned short c) {
  return (unsigned)a | ((unsigned)c << 16);
}

// decode 8 adjacency nibbles of d -> bf16(16 + n) fragments.
// bf16(16+n) = 0x4180 | (n<<3), exact for n in [0,15].
// consumers must subtract 16*colsum(B) from the MFMA result.
union U16x8 { uint4 u; s16x8 s; };
__device__ __forceinline__ s16x8 dec8(unsigned d) {
  U16x8 o;
  o.u.x = 0x41804180u | ((d & 0x0000000Fu) << 3)  | ((d & 0x000000F0u) << 15);
  o.u.y = 0x41804180u | ((d & 0x00000F00u) >> 5)  | ((d & 0x0000F000u) << 7);
  o.u.z = 0x41804180u | ((d & 0x000F0000u) >> 13) | ((d & 0x00F00000u) >> 1);
  o.u.w = 0x41804180u | ((d & 0x0F000000u) >> 21) | ((d & 0xF0000000u) >> 9);
  return o.s;
}

struct Params {
  const void* x; const void* ei;
  const void *wl1, *bl1, *wr1, *br1, *wro1, *wp, *bp;
  const void *wr2, *br2, *wro2, *wl2, *bl2, *wl3, *bl3;
  float* out; float* ws;
};

__device__ __forceinline__ float ldf(const void* p, int i, bool bf) {
  return bf ? bf2f(((const unsigned short*)p)[i]) : ((const float*)p)[i];
}

// ---- LDS (81920 B total => 2 blocks/CU) ----
// A [0,33792):     adj u4 [256 rows][132 B] (P0->P5); after B6: tail bufs + FG
//   tail: oadjb@2048 ddb@6144 caf@6208 psf@6272 qsf@6400 rb@8256 yb@8384 lgb@8512
//   FG:   rel2f@9216 root2f@13312 lin2f@17408 lin3f@21504 brel2f@22784
//         blin2f@22912 blin3f@23040
//   jobs: pbuf@24576 ssA@30720
// B [33792,50688): h0T bf16 [32][264] (P1->Pz1); h1Th [32][264] (4a->P6)
// C [50688,67584): W1T bf16 [32][136] (P0->P1); zT [32][264] (Pz1->4a);
//                  sTh [16][264] (4c->P6)
// D [67584,76032): wrelTh + wrootT [32][40] + blin1f (P0->Pz1);
//                  taT [16][264] (P5->P6)
// E [76032,81920): wpoolTh [16][36] (P0->4c);
//                  colzF[32]@78336 colsF[16]@78464 scrE[16]@78528 bpf[16]@78592
//                  flg[2]@78656 brel1h[32]@81856
#define SMEM_TOTAL 81920

__global__ __launch_bounds__(1024, 8) void mincut_main(Params P) {
  extern __shared__ char smem[];
  const int t = threadIdx.x;
  const int b = blockIdx.x;

  const int wv = t >> 6, lane = t & 63;
  const int lm = lane & 15, quad = lane >> 4;
  const int mbase = wv * 16;

  // ---- Bf: PARALLEL dtype detection (one load per lane, ballot reduce) ----
  int* flg = (int*)(smem + 78656);
  if (wv == 0) {
    const unsigned short* pw = (const unsigned short*)P.wr1;
    unsigned e = (pw[lane] >> 7) & 0xFFu;
    unsigned long long m = __ballot(e > 96u && e < 132u);
    if (lane == 0) flg[0] = (__popcll(m) >= 56) ? 1 : 0;
  } else if (wv == 1) {
    const int* pi = (const int*)P.ei + EPG;
    bool c = false;
    if (lane < 32) { int v = pi[lane]; c = (v >= 256 && v < 512); }
    unsigned long long m = __ballot(c);
    if (lane == 0) flg[1] = (__popcll(m) < 24) ? 1 : 0;
  }

  // A tail
  float* oadjb  = (float*)(smem + 2048);
  float* ddb    = (float*)(smem + 6144);
  float* caf    = (float*)(smem + 6208);
  float* psf    = (float*)(smem + 6272);
  float* qsf    = (float*)(smem + 6400);
  float* rb     = (float*)(smem + 8256);
  float* yb     = (float*)(smem + 8384);
  float* lgb    = (float*)(smem + 8512);
  float* rel2f  = (float*)(smem + 9216);
  float* root2f = (float*)(smem + 13312);
  float* lin2f  = (float*)(smem + 17408);
  float* lin3f  = (float*)(smem + 21504);
  float* brel2f = (float*)(smem + 22784);
  float* blin2f = (float*)(smem + 22912);
  float* blin3f = (float*)(smem + 23040);
  float* pbuf   = (float*)(smem + 24576);
  float* ssA    = (float*)(smem + 30720);
  // B
  unsigned short* h0T  = (unsigned short*)(smem + 33792);
  unsigned short* h1Th = (unsigned short*)(smem + 33792);
  // C
  unsigned short* w1t  = (unsigned short*)(smem + 50688);
  unsigned short* zT   = (unsigned short*)(smem + 50688);
  unsigned short* sTh  = (unsigned short*)(smem + 50688);
  // D
  unsigned short* wrelTh = (unsigned short*)(smem + 67584);
  unsigned short* wrootT = (unsigned short*)(smem + 72704);
  float* blin1f = (float*)(smem + 75264);   // 32 f (dead after P1)
  unsigned short* taT = (unsigned short*)(smem + 67584);
  // E
  unsigned short* wpoolTh = (unsigned short*)(smem + 76032); // [16][36]
  float*          colzF   = (float*)(smem + 78336);          // [32]
  float*          colsF   = (float*)(smem + 78464);          // [16]
  float*          scrE    = (float*)(smem + 78528);          // [16] den scratch
  float*          bpf     = (float*)(smem + 78592);          // [16]
  unsigned short* brel1h  = (unsigned short*)(smem + 81856); // 32 bf16

  // ---- zero adj (u4) + corr bufs (LDS only) ----
  {
    uint4 z = {0u, 0u, 0u, 0u};
    for (int i = t; i < 2112; i += 1024) ((uint4*)smem)[i] = z;
  }
  if (t < 48) colzF[t] = 0.f;   // colzF[32] + colsF[16], contiguous
  __syncthreads();   // B0a: adj zeroed, flags ready

  const bool BF  = (flg[0] != 0);
  const bool I64 = (flg[1] != 0);

  // ---- overlapped front window: edge loads -> weights (incl. FG to regs) -> atomics -> x ----
  // 1) issue ALL edge loads into registers FIRST (oldest in the memory queue)
  uint4 ea0, ea1, ea2, ea3, eb0, eb1, eb2, eb3;
  if (I64) {
    const uint4* s4 = (const uint4*)((const long long*)P.ei + (size_t)b * EPG) + t * 4;
    const uint4* d4 = (const uint4*)((const long long*)P.ei + (size_t)NB * EPG + (size_t)b * EPG) + t * 4;
    ea0 = s4[0]; ea1 = s4[1]; ea2 = s4[2]; ea3 = s4[3];
    eb0 = d4[0]; eb1 = d4[1]; eb2 = d4[2]; eb3 = d4[3];
  } else {
    const uint4* s4 = (const uint4*)((const int*)P.ei + (size_t)b * EPG) + t * 2;
    const uint4* d4 = (const uint4*)((const int*)P.ei + (size_t)NB * EPG + (size_t)b * EPG) + t * 2;
    ea0 = s4[0]; ea1 = s4[1];
    eb0 = d4[0]; eb1 = d4[1];
  }

  // 2) weight staging (global-load latency overlaps the edge loads above)
  for (int e = t; e < 4096; e += 1024) {
    int k = e >> 5, c = e & 31;
    w1t[c * 136 + k] = f2bf(ldf(P.wl1, e, BF));
  }
  {
    int k = t >> 5, c = t & 31;
    wrelTh[c * 40 + k] = f2bf(ldf(P.wr1, t, BF));
    wrootT[c * 40 + k] = f2bf(ldf(P.wro1, t, BF));
  }
  if (t < 512) {
    int m = t >> 4, c = t & 15;
    wpoolTh[c * 36 + m] = f2bf(ldf(P.wp, t, BF));
  }
  if (t < 32) { blin1f[t] = ldf(P.bl1, t, BF); brel1h[t] = f2bf(ldf(P.br1, t, BF)); }
  if (t < 16) bpf[t] = ldf(P.bp, t, BF);

  // 2b) FG weights into REGISTERS (1 value/thread each; joins the overlapped burst;
  //     P6 becomes pure reg->LDS, removing exposed global latency from B6->B7 phase)
  float fg_rel2  = ldf(P.wr2, t, BF);
  float fg_root2 = ldf(P.wro2, t, BF);
  float fg_lin2  = ldf(P.wl2, t, BF);
  float fg_lin3  = (t < 320) ? ldf(P.wl3, t, BF) : 0.f;
  float fg_brel2 = (t < 32) ? ldf(P.br2, t, BF) : 0.f;
  float fg_blin2 = (t < 32) ? ldf(P.bl2, t, BF) : 0.f;
  float fg_blin3 = (t < 10) ? ldf(P.bl3, t, BF) : 0.f;

  // 3) adjacency nibble atomics (consume edge regs; LDS only)
  if (I64) {
    #pragma unroll
    for (int i = 0; i < 4; ++i) {
      uint4 a = (i == 0) ? ea0 : (i == 1) ? ea1 : (i == 2) ? ea2 : ea3;
      uint4 c = (i == 0) ? eb0 : (i == 1) ? eb1 : (i == 2) ? eb2 : eb3;
      unsigned n0 = (a.x & 255u) * 264u + (c.x & 255u);
      unsigned n1 = (a.z & 255u) * 264u + (c.z & 255u);
      atomicAdd((unsigned int*)(smem + ((n0 >> 3) << 2)), 1u << ((n0 & 7u) * 4u));
      atomicAdd((unsigned int*)(smem + ((n1 >> 3) << 2)), 1u << ((n1 & 7u) * 4u));
    }
  } else {
    #pragma unroll
    for (int i = 0; i < 2; ++i) {
      uint4 a = (i == 0) ? ea0 : ea1;
      uint4 c = (i == 0) ? eb0 : eb1;
      unsigned n0 = (a.x & 255u) * 264u + (c.x & 255u);
      unsigned n1 = (a.y & 255u) * 264u + (c.y & 255u);
      unsigned n2 = (a.z & 255u) * 264u + (c.z & 255u);
      unsigned n3 = (a.w & 255u) * 264u + (c.w & 255u);
      atomicAdd((unsigned int*)(smem + ((n0 >> 3) << 2)), 1u << ((n0 & 7u) * 4u));
      atomicAdd((unsigned int*)(smem + ((n1 >> 3) << 2)), 1u << ((n1 & 7u) * 4u));
      atomicAdd((unsigned int*)(smem + ((n2 >> 3) << 2)), 1u << ((n2 & 7u) * 4u));
      atomicAdd((unsigned int*)(smem + ((n3 >> 3) << 2)), 1u << ((n3 & 7u) * 4u));
    }
  }

  // 4) x preload into registers (live across B0b; P1 becomes LDS+MFMA only)
  s16x8 xa[4];
  {
    const size_t node = (size_t)(b * 256 + mbase + lm);
    if (BF) {
      #pragma unroll
      for (int ks = 0; ks < 4; ++ks)
        xa[ks] = *(const s16x8*)((const unsigned short*)P.x + node * 128 + ks * 32 + quad * 8);
    } else {
      #pragma unroll
      for (int ks = 0; ks < 4; ++ks) {
        const float* xp = (const float*)P.x + node * 128 + ks * 32 + quad * 8;
        f32x4 v0 = *(const f32x4*)xp;
        f32x4 v1 = *(const f32x4*)(xp + 4);
        #pragma unroll
        for (int j = 0; j < 4; ++j) { xa[ks][j] = (short)f2bf(v0[j]); xa[ks][4 + j] = (short)f2bf(v1[j]); }
      }
    }
  }
  __syncthreads();   // B0b: adj counts + staged weights ready

  // ---- P1: h0 = x @ W1 + b (MFMA) -> h0T bf16 (packed b64 stores) ----
  {
    f32x4 acc[2] = {{0.f,0.f,0.f,0.f},{0.f,0.f,0.f,0.f}};
    #pragma unroll
    for (int ks = 0; ks < 4; ++ks) {
      const int k0 = ks * 32 + quad * 8;
      #pragma unroll
      for (int ct = 0; ct < 2; ++ct) {
        s16x8 bh = *(const s16x8*)(w1t + (ct * 16 + lm) * 136 + k0);
        acc[ct] = __builtin_amdgcn_mfma_f32_16x16x32_bf16(xa[ks], bh, acc[ct], 0, 0, 0);
      }
    }
    #pragma unroll
    for (int ct = 0; ct < 2; ++ct) {
      const int c = ct * 16 + lm;
      float bias = blin1f[c];
      *(uint2*)(h0T + c * 264 + mbase + quad * 4) =
          make_uint2(pk2(f2bf(acc[ct][0] + bias), f2bf(acc[ct][1] + bias)),
                     pk2(f2bf(acc[ct][2] + bias), f2bf(acc[ct][3] + bias)));
    }
  }
  __syncthreads();   // B1: h0T ready

  // ---- Pz1: z = h0@Wrel, r = h0@Wroot; zT + colz atomics ----
  f32x4 racc[2] = {{0.f,0.f,0.f,0.f},{0.f,0.f,0.f,0.f}};
  {
    s16x8 Ah;
    #pragma unroll
    for (int j = 0; j < 8; ++j) Ah[j] = (short)h0T[(quad * 8 + j) * 264 + mbase + lm];
    f32x4 zacc[2] = {{0.f,0.f,0.f,0.f},{0.f,0.f,0.f,0.f}};
    #pragma unroll
    for (int ct = 0; ct < 2; ++ct) {
      const int c = ct * 16 + lm;
      s16x8 brh = *(const s16x8*)(wrelTh + c * 40 + quad * 8);
      s16x8 bro = *(const s16x8*)(wrootT + c * 40 + quad * 8);
      zacc[ct] = __builtin_amdgcn_mfma_f32_16x16x32_bf16(Ah, brh, zacc[ct], 0, 0, 0);
      racc[ct] = __builtin_amdgcn_mfma_f32_16x16x32_bf16(Ah, bro, racc[ct], 0, 0, 0);
    }
    #pragma unroll
    for (int ct = 0; ct < 2; ++ct) {
      unsigned short u0 = f2bf(zacc[ct][0]), u1 = f2bf(zacc[ct][1]);
      unsigned short u2 = f2bf(zacc[ct][2]), u3 = f2bf(zacc[ct][3]);
      *(uint2*)(zT + (ct * 16 + lm) * 264 + mbase + quad * 4) =
          make_uint2(pk2(u0, u1), pk2(u2, u3));
      float pz = (bf2f(u0) + bf2f(u1)) + (bf2f(u2) + bf2f(u3));
      pz += __shfl_xor(pz, 16, 64);
      pz += __shfl_xor(pz, 32, 64);
      if (lane < 16) atomicAdd(colzF + ct * 16 + lm, pz);
    }
  }
  __syncthreads();   // B2: wrelT/wrootT/h0T reads done; colzF complete

  // ---- 4a: h1 = A@z + r + brel - 16*colz ; deg; write h1Th ----
  float degf;
  {
    f32x4 h1acc[2] = { racc[0], racc[1] };   // C-operand carries Pz1 result
    unsigned dsum = 0;
    const char* arow = smem + (mbase + lm) * 132;
    #pragma unroll
    for (int ks = 0; ks < 8; ++ks) {
      unsigned d = *(const unsigned int*)(arow + ks * 16 + quad * 4);
      unsigned v = (d & 0x0F0F0F0Fu) + ((d >> 4) & 0x0F0F0F0Fu);
      dsum += (v * 0x01010101u) >> 24;
      s16x8 af = dec8(d);
      const int v0 = ks * 32 + quad * 8;
      #pragma unroll
      for (int ct = 0; ct < 2; ++ct) {
        s16x8 bz = *(const s16x8*)(zT + (ct * 16 + lm) * 264 + v0);
        h1acc[ct] = __builtin_amdgcn_mfma_f32_16x16x32_bf16(af, bz, h1acc[ct], 0, 0, 0);
      }
    }
    dsum += __shfl_xor(dsum, 16, 64);
    dsum += __shfl_xor(dsum, 32, 64);
    degf = (float)dsum;   // deg of node mbase+lm
    #pragma unroll
    for (int ct = 0; ct < 2; ++ct) {
      const int c = ct * 16 + lm;
      float bias = bf2f(brel1h[c]) - 16.f * colzF[c];   // offset-16 correction
      *(uint2*)(h1Th + c * 264 + mbase + quad * 4) =
          make_uint2(pk2(f2bf(h1acc[ct][0] + bias), f2bf(h1acc[ct][1] + bias)),
                     pk2(f2bf(h1acc[ct][2] + bias), f2bf(h1acc[ct][3] + bias)));
    }
  }
  __syncthreads();   // B4: h1Th ready; zT reads done

  // ---- 4c: s2 = h1@Wpool + bp ; softmax ; sTh ; den partial ----
  {
    s16x8 Ah1;
    #pragma unroll
    for (int j = 0; j < 8; ++j) Ah1[j] = (short)h1Th[(quad * 8 + j) * 264 + mbase + lm];
    s16x8 Bh;
    ((uint2*)&Bh)[0] = *(const uint2*)(wpoolTh + lm * 36 + quad * 8);
    ((uint2*)&Bh)[1] = *(const uint2*)(wpoolTh + lm * 36 + quad * 8 + 4);
    f32x4 lacc = {0.f, 0.f, 0.f, 0.f};
    lacc = __builtin_amdgcn_mfma_f32_16x16x32_bf16(Ah1, Bh, lacc, 0, 0, 0);
    f32x4 lg;
    float bm = bpf[lm];
    #pragma unroll
    for (int r = 0; r < 4; ++r) lg[r] = lacc[r] + bm;
    f32x4 mx = lg;
    #pragma unroll
    for (int m = 1; m <= 8; m <<= 1)
      #pragma unroll
      for (int r = 0; r < 4; ++r) mx[r] = fmaxf(mx[r], __shfl_xor(mx[r], m, 64));
    #pragma unroll
    for (int r = 0; r < 4; ++r) lg[r] = __expf(lg[r] - mx[r]);
    f32x4 sm = lg;
    #pragma unroll
    for (int m = 1; m <= 8; m <<= 1)
      #pragma unroll
      for (int r = 0; r < 4; ++r) sm[r] += __shfl_xor(sm[r], m, 64);
    f32x4 sval, sq;
    #pragma unroll
    for (int r = 0; r < 4; ++r) { sval[r] = lg[r] / sm[r]; sq[r] = sval[r] * sval[r]; }
    #pragma unroll
    for (int m = 1; m <= 8; m <<= 1)
      #pragma unroll
      for (int r = 0; r < 4; ++r) sq[r] += __shfl_xor(sq[r], m, 64);
    // sTh packed writes + cols atomics
    {
      unsigned short h0s = f2bf(sval[0]);
      unsigned short h1s = f2bf(sval[1]);
      unsigned short h2s = f2bf(sval[2]);
      unsigned short h3s = f2bf(sval[3]);
      const int nb = lm * 264 + mbase + quad * 4;
      *(uint2*)(sTh + nb) = make_uint2(pk2(h0s, h1s), pk2(h2s, h3s));
      float sr = (bf2f(h0s) + bf2f(h1s)) + (bf2f(h2s) + bf2f(h3s));
      sr += __shfl_xor(sr, 16, 64);
      sr += __shfl_xor(sr, 32, 64);
      if (lane < 16) atomicAdd(colsF + lm, sr);
    }
    // den partial: node mbase+l (l<16): ssq from quad l>>2, slot l&3
    {
      int l = lane & 15, src = (l >> 2) << 4;
      float q0 = __shfl(sq[0], src, 64), q1 = __shfl(sq[1], src, 64);
      float q2 = __shfl(sq[2], src, 64), q3 = __shfl(sq[3], src, 64);
      float ssel = (l & 2) ? ((l & 1) ? q3 : q2) : ((l & 1) ? q1 : q0);
      float vden = (lane < 16) ? degf * ssel : 0.f;
      #pragma unroll
      for (int o = 32; o > 0; o >>= 1) vden += __shfl_xor(vden, o, 64);
      if (lane == 0) scrE[wv] = vden;
    }
  }
  __syncthreads();   // B5: sTh ready; colsF complete

  // ---- P5: tA = A@s -> taT bf16 (adj re-read from LDS, magic decode) ----
  {
    float cols = colsF[lm];
    f32x4 tacc = {0.f, 0.f, 0.f, 0.f};
    const char* arow = smem + (mbase + lm) * 132;
    #pragma unroll
    for (int ks = 0; ks < 8; ++ks) {
      unsigned d = *(const unsigned int*)(arow + ks * 16 + quad * 4);
      s16x8 af = dec8(d);
      const int v0 = ks * 32 + quad * 8;
      s16x8 bh = *(const s16x8*)(sTh + lm * 264 + v0);
      tacc = __builtin_amdgcn_mfma_f32_16x16x32_bf16(af, bh, tacc, 0, 0, 0);
    }
    float c16 = 16.f * cols;                            // offset-16 correction
    *(uint2*)(taT + lm * 264 + mbase + quad * 4) =
        make_uint2(pk2(f2bf(tacc[0] - c16), f2bf(tacc[1] - c16)),
                   pk2(f2bf(tacc[2] - c16), f2bf(tacc[3] - c16)));
  }
  __syncthreads();   // B6: adjacency dead

  // ---- P6: FG weights reg -> LDS (no global loads) + 4 MFMA reduction jobs ----
  rel2f[t] = fg_rel2;
  root2f[t] = fg_root2;
  lin2f[t] = fg_lin2;
  if (t < 320) lin3f[t] = fg_lin3;
  if (t < 32) brel2f[t] = fg_brel2;
  if (t < 32) blin2f[t] = fg_blin2;
  if (t < 10) blin3f[t] = fg_blin3;

  if (wv < 4) {
    const unsigned short* Ap = sTh;
    const unsigned short* Bp; float* dst; int W, ct = 0;
    switch (wv) {
      case 0: Bp = h1Th; dst = pbuf;  W = 32; ct = 0; break;
      case 1: Bp = h1Th; dst = pbuf;  W = 32; ct = 1; break;
      case 2: Bp = taT;  dst = oadjb; W = 16; break;
      default: Bp = sTh; dst = ssA;   W = 16; break;
    }
    const int cidx = ct * 16 + lm;
    const unsigned short* Bb = Bp + cidx * 264;
    f32x4 acc = {0.f, 0.f, 0.f, 0.f};
    #pragma unroll
    for (int ch = 0; ch < 8; ++ch) {
      s16x8 a = *(const s16x8*)(Ap + lm * 264 + ch * 32 + quad * 8);
      s16x8 bb = *(const s16x8*)(Bb + ch * 32 + quad * 8);
      acc = __builtin_amdgcn_mfma_f32_16x16x32_bf16(a, bb, acc, 0, 0, 0);
    }
    #pragma unroll
    for (int r = 0; r < 4; ++r) dst[(quad * 4 + r) * W + cidx] = acc[r];
  }
  __syncthreads();   // B7 — LAST barrier

  // ---- tail: wave0 = output chain (intra-wave), wave1 = loss chain ----
  if (wv == 0) {
    // degree vector of pooled adj (row sums excluding diag)
    if (lane < 16) {
      float rs = 0.f;
      #pragma unroll
      for (int j = 0; j < 16; ++j) if (j != lane) rs += oadjb[lane * 16 + j];
      ddb[lane] = sqrtf(rs) + 1e-15f;
    }
    // colsums of normalized adj (never materialize the matrix)
    if (lane < 16) {
      float s = 0.f;
      float dj = ddb[lane];
      #pragma unroll
      for (int k = 0; k < 16; ++k)
        if (k != lane) s += oadjb[k * 16 + lane] / (ddb[k] * dj);
      caf[lane] = s;
    }
    // ps = colsum(pbuf), qs = ca^T pbuf   (readout-sum commuted past conv2)
    if (lane < 32) {
      float ps = 0.f, qs = 0.f;
      #pragma unroll
      for (int j = 0; j < 16; ++j) {
        float pv = pbuf[j * 32 + lane];
        ps += pv;
        qs += caf[j] * pv;
      }
      psf[lane] = ps; qsf[lane] = qs;
    }
    // r = 16*brel2 + qs@Wrel2 + ps@Wroot2
    if (lane < 32) {
      float r = 16.f * brel2f[lane];
      #pragma unroll
      for (int m = 0; m < 32; ++m)
        r += qsf[m] * rel2f[m * 32 + lane] + psf[m] * root2f[m * 32 + lane];
      rb[lane] = r;
    }
    if (lane < 32) {
      float y = blin2f[lane];
      #pragma unroll
      for (int m = 0; m < 32; ++m) y += rb[m] * lin2f[m * 32 + lane];
      yb[lane] = fmaxf(y, 0.f);
    }
    if (lane < 10) {
      float lg = blin3f[lane];
      #pragma unroll
      for (int m = 0; m < 32; ++m) lg += yb[m] * lin3f[m * 10 + lane];
      lgb[lane] = lg;
    }
    if (lane == 0) {
      float mx = lgb[0];
      #pragma unroll
      for (int i = 1; i < 10; ++i) mx = fmaxf(mx, lgb[i]);
      float sum = 0.f;
      #pragma unroll
      for (int i = 0; i < 10; ++i) sum += __expf(lgb[i] - mx);
      lgb[10] = mx + __logf(sum);
    }
    if (lane < 10) {
      float val = lgb[lane] - lgb[10];
      if (BF) ((unsigned short*)P.out)[b * 10 + lane] = f2bf(val);
      else    P.out[b * 10 + lane] = val;
    }
  } else if (wv == 1) {
    float vfro = 0.f, vtr = 0.f;
    #pragma unroll
    for (int u = 0; u < 4; ++u) {
      int i = lane * 4 + u, k = i >> 4, j = i & 15;
      float ssv = ssA[i];
      vfro += ssv * ssv;
      if (k == j) vtr += ssv;
    }
    float vnum = (lane < 16) ? oadjb[lane * 17] : 0.f;
    float vden = (lane < 16) ? scrE[lane] : 0.f;
    #pragma unroll
    for (int o = 32; o > 0; o >>= 1) {
      vfro += __shfl_xor(vfro, o, 64);
      vtr  += __shfl_xor(vtr, o, 64);
      vnum += __shfl_xor(vnum, o, 64);
      vden += __shfl_xor(vden, o, 64);
    }
    if (lane == 0) {
      float ssn = sqrtf(vfro);
      float orth2 = 2.f - vtr / (2.f * ssn);
      atomicAdd(P.ws, -(vnum / vden) * (1.f / NB));
      atomicAdd(P.ws + 1, sqrtf(fmaxf(orth2, 0.f)) * (1.f / NB));
      // completion counter: last block writes the loss outputs (folds mincut_fin)
      __threadfence();
      unsigned old = atomicAdd((unsigned int*)(P.ws + 2), 1u);
      if (old == (unsigned)(NB - 1)) {
        float l0 = atomicAdd(P.ws, 0.f);      // coherent RMW reads
        float l1 = atomicAdd(P.ws + 1, 0.f);
        if (BF) {
          ((unsigned short*)P.out)[5120] = f2bf(l0);
          ((unsigned short*)P.out)[5121] = f2bf(l1);
        } else {
          P.out[5120] = l0;
          P.out[5121] = l1;
        }
      }
    }
  }
}

extern "C" void kernel_launch(void* const* d_in, const int* in_sizes, int n_in,
                              void* d_out, int out_size, void* d_ws, size_t ws_size,
                              hipStream_t stream) {
  (void)in_sizes; (void)n_in; (void)out_size; (void)ws_size;
  Params P;
  P.x    = d_in[0];
  P.ei   = d_in[1];
  P.wl1  = d_in[3];
  P.bl1  = d_in[4];
  P.wr1  = d_in[5];
  P.br1  = d_in[6];
  P.wro1 = d_in[7];
  P.wp   = d_in[8];
  P.bp   = d_in[9];
  P.wr2  = d_in[10];
  P.br2  = d_in[11];
  P.wro2 = d_in[12];
  P.wl2  = d_in[13];
  P.bl2  = d_in[14];
  P.wl3  = d_in[15];
  P.bl3  = d_in[16];
  P.out  = (float*)d_out;
  P.ws   = (float*)d_ws;

  hipMemsetAsync(d_ws, 0, 4 * sizeof(float), stream);
  hipFuncSetAttribute(reinterpret_cast<const void*>(mincut_main),
                      hipFuncAttributeMaxDynamicSharedMemorySize, SMEM_TOTAL);
  hipLaunchKernelGGL(mincut_main, dim3(NB), dim3(1024), SMEM_TOTAL, stream, P);
}

// Round 10
// 164.825 us; speedup vs baseline: 1.0457x; 1.0083x over previous
//
#include <hip/hip_runtime.h>

#define NB 512
#define NN 256
#define EPG 8192
#define FINC 128

typedef float f32x4 __attribute__((ext_vector_type(4)));
typedef short s16x8 __attribute__((ext_vector_type(8)));

__device__ __forceinline__ float bf2f(unsigned short u) {
  union { unsigned int i; float f; } x; x.i = ((unsigned int)u) << 16; return x.f;
}
__device__ __forceinline__ unsigned short f2bf(float f) {
  union { float f; unsigned int i; } x; x.f = f;
  unsigned int r = x.i + 0x7fffu + ((x.i >> 16) & 1u);
  return (unsigned short)(r >> 16);
}
__device__ __forceinline__ unsigned pk2(unsigned short a, unsigned short c) {
  return (unsigned)a | ((unsigned)c << 16);
}

// DPP row-rotate (within 16-lane row), VALU pipe — replaces ds_bpermute shuffles
// for 16-lane reductions. ctrl: row_ror:N = 0x120|N.
template<int C>
__device__ __forceinline__ float rorf(float v) {
  return __int_as_float(__builtin_amdgcn_update_dpp(
      0, __float_as_int(v), C, 0xF, 0xF, true));
}

// decode 8 adjacency nibbles of d -> bf16(16 + n) fragments.
// bf16(16+n) = 0x4180 | (n<<3), exact for n in [0,15].
// consumers must subtract 16*colsum(B) from the MFMA result.
union U16x8 { uint4 u; s16x8 s; };
__device__ __forceinline__ s16x8 dec8(unsigned d) {
  U16x8 o;
  o.u.x = 0x41804180u | ((d & 0x0000000Fu) << 3)  | ((d & 0x000000F0u) << 15);
  o.u.y = 0x41804180u | ((d & 0x00000F00u) >> 5)  | ((d & 0x0000F000u) << 7);
  o.u.z = 0x41804180u | ((d & 0x000F0000u) >> 13) | ((d & 0x00F00000u) >> 1);
  o.u.w = 0x41804180u | ((d & 0x0F000000u) >> 21) | ((d & 0xF0000000u) >> 9);
  return o.s;
}

struct Params {
  const void* x; const void* ei;
  const void *wl1, *bl1, *wr1, *br1, *wro1, *wp, *bp;
  const void *wr2, *br2, *wro2, *wl2, *bl2, *wl3, *bl3;
  float* out; float* ws;
};

__device__ __forceinline__ float ldf(const void* p, int i, bool bf) {
  return bf ? bf2f(((const unsigned short*)p)[i]) : ((const float*)p)[i];
}

// ---- LDS (81920 B total => 2 blocks/CU) ----
// A [0,33792):     adj u4 [256 rows][132 B] (P0->P5); after B6: tail bufs + FG
//   tail: oadjb@2048 ddb@6144 caf@6208 psf@6272 qsf@6400 rb@8256 yb@8384 lgb@8512
//   FG:   rel2f@9216 root2f@13312 lin2f@17408 lin3f@21504 brel2f@22784
//         blin2f@22912 blin3f@23040
//   jobs: pbuf@24576 ssA@30720
// B [33792,50688): h0T bf16 [32][264] (P1->Pz1); h1Th [32][264] (4a->P6)
// C [50688,67584): W1T bf16 [32][136] (P0->P1); zT [32][264] (Pz1->4a);
//                  sTh [16][264] (4c->P6)
// D [67584,76032): wrelTh + wrootT [32][40] + blin1f (P0->Pz1);
//                  taT [16][264] (P5->P6)
// E [76032,81920): wpoolTh [16][36] (P0->4c);
//                  colzF[32]@78336 colsF[16]@78464 scrE[16]@78528 bpf[16]@78592
//                  flg[2]@78656 brel1h[32]@81856
#define SMEM_TOTAL 81920

__global__ __launch_bounds__(1024, 8) void mincut_main(Params P) {
  extern __shared__ char smem[];
  const int t = threadIdx.x;
  const int b = blockIdx.x;

  const int wv = t >> 6, lane = t & 63;
  const int lm = lane & 15, quad = lane >> 4;
  const int mbase = wv * 16;

  // ---- Bf: PARALLEL dtype detection (one load per lane, ballot reduce) ----
  int* flg = (int*)(smem + 78656);
  if (wv == 0) {
    const unsigned short* pw = (const unsigned short*)P.wr1;
    unsigned e = (pw[lane] >> 7) & 0xFFu;
    unsigned long long m = __ballot(e > 96u && e < 132u);
    if (lane == 0) flg[0] = (__popcll(m) >= 56) ? 1 : 0;
  } else if (wv == 1) {
    const int* pi = (const int*)P.ei + EPG;
    bool c = false;
    if (lane < 32) { int v = pi[lane]; c = (v >= 256 && v < 512); }
    unsigned long long m = __ballot(c);
    if (lane == 0) flg[1] = (__popcll(m) < 24) ? 1 : 0;
  }

  // A tail
  float* oadjb  = (float*)(smem + 2048);
  float* ddb    = (float*)(smem + 6144);
  float* caf    = (float*)(smem + 6208);
  float* psf    = (float*)(smem + 6272);
  float* qsf    = (float*)(smem + 6400);
  float* rb     = (float*)(smem + 8256);
  float* yb     = (float*)(smem + 8384);
  float* lgb    = (float*)(smem + 8512);
  float* rel2f  = (float*)(smem + 9216);
  float* root2f = (float*)(smem + 13312);
  float* lin2f  = (float*)(smem + 17408);
  float* lin3f  = (float*)(smem + 21504);
  float* brel2f = (float*)(smem + 22784);
  float* blin2f = (float*)(smem + 22912);
  float* blin3f = (float*)(smem + 23040);
  float* pbuf   = (float*)(smem + 24576);
  float* ssA    = (float*)(smem + 30720);
  // B
  unsigned short* h0T  = (unsigned short*)(smem + 33792);
  unsigned short* h1Th = (unsigned short*)(smem + 33792);
  // C
  unsigned short* w1t  = (unsigned short*)(smem + 50688);
  unsigned short* zT   = (unsigned short*)(smem + 50688);
  unsigned short* sTh  = (unsigned short*)(smem + 50688);
  // D
  unsigned short* wrelTh = (unsigned short*)(smem + 67584);
  unsigned short* wrootT = (unsigned short*)(smem + 72704);
  float* blin1f = (float*)(smem + 75264);   // 32 f (dead after P1)
  unsigned short* taT = (unsigned short*)(smem + 67584);
  // E
  unsigned short* wpoolTh = (unsigned short*)(smem + 76032); // [16][36]
  float*          colzF   = (float*)(smem + 78336);          // [32]
  float*          colsF   = (float*)(smem + 78464);          // [16]
  float*          scrE    = (float*)(smem + 78528);          // [16] den scratch
  float*          bpf     = (float*)(smem + 78592);          // [16]
  unsigned short* brel1h  = (unsigned short*)(smem + 81856); // 32 bf16

  // ---- zero adj (u4) + corr bufs (LDS only) ----
  {
    uint4 z = {0u, 0u, 0u, 0u};
    for (int i = t; i < 2112; i += 1024) ((uint4*)smem)[i] = z;
  }
  if (t < 48) colzF[t] = 0.f;   // colzF[32] + colsF[16], contiguous
  __syncthreads();   // B0a: adj zeroed, flags ready

  const bool BF  = (flg[0] != 0);
  const bool I64 = (flg[1] != 0);

  // ---- overlapped front window: edge loads -> weights (incl. FG to regs) -> atomics -> x ----
  // 1) issue ALL edge loads into registers FIRST (oldest in the memory queue)
  uint4 ea0, ea1, ea2, ea3, eb0, eb1, eb2, eb3;
  if (I64) {
    const uint4* s4 = (const uint4*)((const long long*)P.ei + (size_t)b * EPG) + t * 4;
    const uint4* d4 = (const uint4*)((const long long*)P.ei + (size_t)NB * EPG + (size_t)b * EPG) + t * 4;
    ea0 = s4[0]; ea1 = s4[1]; ea2 = s4[2]; ea3 = s4[3];
    eb0 = d4[0]; eb1 = d4[1]; eb2 = d4[2]; eb3 = d4[3];
  } else {
    const uint4* s4 = (const uint4*)((const int*)P.ei + (size_t)b * EPG) + t * 2;
    const uint4* d4 = (const uint4*)((const int*)P.ei + (size_t)NB * EPG + (size_t)b * EPG) + t * 2;
    ea0 = s4[0]; ea1 = s4[1];
    eb0 = d4[0]; eb1 = d4[1];
  }

  // 2) weight staging (global-load latency overlaps the edge loads above)
  for (int e = t; e < 4096; e += 1024) {
    int k = e >> 5, c = e & 31;
    w1t[c * 136 + k] = f2bf(ldf(P.wl1, e, BF));
  }
  {
    int k = t >> 5, c = t & 31;
    wrelTh[c * 40 + k] = f2bf(ldf(P.wr1, t, BF));
    wrootT[c * 40 + k] = f2bf(ldf(P.wro1, t, BF));
  }
  if (t < 512) {
    int m = t >> 4, c = t & 15;
    wpoolTh[c * 36 + m] = f2bf(ldf(P.wp, t, BF));
  }
  if (t < 32) { blin1f[t] = ldf(P.bl1, t, BF); brel1h[t] = f2bf(ldf(P.br1, t, BF)); }
  if (t < 16) bpf[t] = ldf(P.bp, t, BF);

  // 2b) FG weights into REGISTERS (1 value/thread each; joins the overlapped burst;
  //     P6 becomes pure reg->LDS, removing exposed global latency from B6->B7 phase)
  float fg_rel2  = ldf(P.wr2, t, BF);
  float fg_root2 = ldf(P.wro2, t, BF);
  float fg_lin2  = ldf(P.wl2, t, BF);
  float fg_lin3  = (t < 320) ? ldf(P.wl3, t, BF) : 0.f;
  float fg_brel2 = (t < 32) ? ldf(P.br2, t, BF) : 0.f;
  float fg_blin2 = (t < 32) ? ldf(P.bl2, t, BF) : 0.f;
  float fg_blin3 = (t < 10) ? ldf(P.bl3, t, BF) : 0.f;

  // 3) adjacency nibble atomics (consume edge regs; LDS only)
  if (I64) {
    #pragma unroll
    for (int i = 0; i < 4; ++i) {
      uint4 a = (i == 0) ? ea0 : (i == 1) ? ea1 : (i == 2) ? ea2 : ea3;
      uint4 c = (i == 0) ? eb0 : (i == 1) ? eb1 : (i == 2) ? eb2 : eb3;
      unsigned n0 = (a.x & 255u) * 264u + (c.x & 255u);
      unsigned n1 = (a.z & 255u) * 264u + (c.z & 255u);
      atomicAdd((unsigned int*)(smem + ((n0 >> 3) << 2)), 1u << ((n0 & 7u) * 4u));
      atomicAdd((unsigned int*)(smem + ((n1 >> 3) << 2)), 1u << ((n1 & 7u) * 4u));
    }
  } else {
    #pragma unroll
    for (int i = 0; i < 2; ++i) {
      uint4 a = (i == 0) ? ea0 : ea1;
      uint4 c = (i == 0) ? eb0 : eb1;
      unsigned n0 = (a.x & 255u) * 264u + (c.x & 255u);
      unsigned n1 = (a.y & 255u) * 264u + (c.y & 255u);
      unsigned n2 = (a.z & 255u) * 264u + (c.z & 255u);
      unsigned n3 = (a.w & 255u) * 264u + (c.w & 255u);
      atomicAdd((unsigned int*)(smem + ((n0 >> 3) << 2)), 1u << ((n0 & 7u) * 4u));
      atomicAdd((unsigned int*)(smem + ((n1 >> 3) << 2)), 1u << ((n1 & 7u) * 4u));
      atomicAdd((unsigned int*)(smem + ((n2 >> 3) << 2)), 1u << ((n2 & 7u) * 4u));
      atomicAdd((unsigned int*)(smem + ((n3 >> 3) << 2)), 1u << ((n3 & 7u) * 4u));
    }
  }

  // 4) x preload into registers (live across B0b; P1 becomes LDS+MFMA only)
  s16x8 xa[4];
  {
    const size_t node = (size_t)(b * 256 + mbase + lm);
    if (BF) {
      #pragma unroll
      for (int ks = 0; ks < 4; ++ks)
        xa[ks] = *(const s16x8*)((const unsigned short*)P.x + node * 128 + ks * 32 + quad * 8);
    } else {
      #pragma unroll
      for (int ks = 0; ks < 4; ++ks) {
        const float* xp = (const float*)P.x + node * 128 + ks * 32 + quad * 8;
        f32x4 v0 = *(const f32x4*)xp;
        f32x4 v1 = *(const f32x4*)(xp + 4);
        #pragma unroll
        for (int j = 0; j < 4; ++j) { xa[ks][j] = (short)f2bf(v0[j]); xa[ks][4 + j] = (short)f2bf(v1[j]); }
      }
    }
  }
  __syncthreads();   // B0b: adj counts + staged weights ready

  // ---- P1: h0 = x @ W1 + b (MFMA) -> h0T bf16 (packed b64 stores) ----
  {
    f32x4 acc[2] = {{0.f,0.f,0.f,0.f},{0.f,0.f,0.f,0.f}};
    #pragma unroll
    for (int ks = 0; ks < 4; ++ks) {
      const int k0 = ks * 32 + quad * 8;
      #pragma unroll
      for (int ct = 0; ct < 2; ++ct) {
        s16x8 bh = *(const s16x8*)(w1t + (ct * 16 + lm) * 136 + k0);
        acc[ct] = __builtin_amdgcn_mfma_f32_16x16x32_bf16(xa[ks], bh, acc[ct], 0, 0, 0);
      }
    }
    #pragma unroll
    for (int ct = 0; ct < 2; ++ct) {
      const int c = ct * 16 + lm;
      float bias = blin1f[c];
      *(uint2*)(h0T + c * 264 + mbase + quad * 4) =
          make_uint2(pk2(f2bf(acc[ct][0] + bias), f2bf(acc[ct][1] + bias)),
                     pk2(f2bf(acc[ct][2] + bias), f2bf(acc[ct][3] + bias)));
    }
  }
  __syncthreads();   // B1: h0T ready

  // ---- Pz1: z = h0@Wrel, r = h0@Wroot; zT + colz atomics ----
  f32x4 racc[2] = {{0.f,0.f,0.f,0.f},{0.f,0.f,0.f,0.f}};
  {
    s16x8 Ah;
    #pragma unroll
    for (int j = 0; j < 8; ++j) Ah[j] = (short)h0T[(quad * 8 + j) * 264 + mbase + lm];
    f32x4 zacc[2] = {{0.f,0.f,0.f,0.f},{0.f,0.f,0.f,0.f}};
    #pragma unroll
    for (int ct = 0; ct < 2; ++ct) {
      const int c = ct * 16 + lm;
      s16x8 brh = *(const s16x8*)(wrelTh + c * 40 + quad * 8);
      s16x8 bro = *(const s16x8*)(wrootT + c * 40 + quad * 8);
      zacc[ct] = __builtin_amdgcn_mfma_f32_16x16x32_bf16(Ah, brh, zacc[ct], 0, 0, 0);
      racc[ct] = __builtin_amdgcn_mfma_f32_16x16x32_bf16(Ah, bro, racc[ct], 0, 0, 0);
    }
    #pragma unroll
    for (int ct = 0; ct < 2; ++ct) {
      unsigned short u0 = f2bf(zacc[ct][0]), u1 = f2bf(zacc[ct][1]);
      unsigned short u2 = f2bf(zacc[ct][2]), u3 = f2bf(zacc[ct][3]);
      *(uint2*)(zT + (ct * 16 + lm) * 264 + mbase + quad * 4) =
          make_uint2(pk2(u0, u1), pk2(u2, u3));
      float pz = (bf2f(u0) + bf2f(u1)) + (bf2f(u2) + bf2f(u3));
      pz += __shfl_xor(pz, 16, 64);
      pz += __shfl_xor(pz, 32, 64);
      if (lane < 16) atomicAdd(colzF + ct * 16 + lm, pz);
    }
  }
  __syncthreads();   // B2: wrelT/wrootT/h0T reads done; colzF complete

  // ---- 4a: h1 = A@z + r + brel - 16*colz ; deg; write h1Th ----
  float degf;
  {
    f32x4 h1acc[2] = { racc[0], racc[1] };   // C-operand carries Pz1 result
    unsigned dsum = 0;
    const char* arow = smem + (mbase + lm) * 132;
    #pragma unroll
    for (int ks = 0; ks < 8; ++ks) {
      unsigned d = *(const unsigned int*)(arow + ks * 16 + quad * 4);
      unsigned v = (d & 0x0F0F0F0Fu) + ((d >> 4) & 0x0F0F0F0Fu);
      dsum += (v * 0x01010101u) >> 24;
      s16x8 af = dec8(d);
      const int v0 = ks * 32 + quad * 8;
      #pragma unroll
      for (int ct = 0; ct < 2; ++ct) {
        s16x8 bz = *(const s16x8*)(zT + (ct * 16 + lm) * 264 + v0);
        h1acc[ct] = __builtin_amdgcn_mfma_f32_16x16x32_bf16(af, bz, h1acc[ct], 0, 0, 0);
      }
    }
    dsum += __shfl_xor(dsum, 16, 64);
    dsum += __shfl_xor(dsum, 32, 64);
    degf = (float)dsum;   // deg of node mbase+lm
    #pragma unroll
    for (int ct = 0; ct < 2; ++ct) {
      const int c = ct * 16 + lm;
      float bias = bf2f(brel1h[c]) - 16.f * colzF[c];   // offset-16 correction
      *(uint2*)(h1Th + c * 264 + mbase + quad * 4) =
          make_uint2(pk2(f2bf(h1acc[ct][0] + bias), f2bf(h1acc[ct][1] + bias)),
                     pk2(f2bf(h1acc[ct][2] + bias), f2bf(h1acc[ct][3] + bias)));
    }
  }
  __syncthreads();   // B4: h1Th ready; zT reads done

  // ---- 4c: s2 = h1@Wpool + bp ; softmax (DPP row_ror) ; sTh ; den partial ----
  {
    s16x8 Ah1;
    #pragma unroll
    for (int j = 0; j < 8; ++j) Ah1[j] = (short)h1Th[(quad * 8 + j) * 264 + mbase + lm];
    s16x8 Bh;
    ((uint2*)&Bh)[0] = *(const uint2*)(wpoolTh + lm * 36 + quad * 8);
    ((uint2*)&Bh)[1] = *(const uint2*)(wpoolTh + lm * 36 + quad * 8 + 4);
    f32x4 lacc = {0.f, 0.f, 0.f, 0.f};
    lacc = __builtin_amdgcn_mfma_f32_16x16x32_bf16(Ah1, Bh, lacc, 0, 0, 0);
    f32x4 lg;
    float bm = bpf[lm];
    #pragma unroll
    for (int r = 0; r < 4; ++r) lg[r] = lacc[r] + bm;
    // 16-lane row reductions on the VALU pipe via DPP row_ror (no ds_bpermute)
    #pragma unroll
    for (int r = 0; r < 4; ++r) {
      float m = lg[r];
      m = fmaxf(m, rorf<0x121>(m));
      m = fmaxf(m, rorf<0x122>(m));
      m = fmaxf(m, rorf<0x124>(m));
      m = fmaxf(m, rorf<0x128>(m));
      lg[r] = __expf(lg[r] - m);
    }
    f32x4 sm;
    #pragma unroll
    for (int r = 0; r < 4; ++r) {
      float s = lg[r];
      s += rorf<0x121>(s); s += rorf<0x122>(s); s += rorf<0x124>(s); s += rorf<0x128>(s);
      sm[r] = s;
    }
    f32x4 sval, sq;
    #pragma unroll
    for (int r = 0; r < 4; ++r) { sval[r] = lg[r] / sm[r]; sq[r] = sval[r] * sval[r]; }
    #pragma unroll
    for (int r = 0; r < 4; ++r) {
      float s = sq[r];
      s += rorf<0x121>(s); s += rorf<0x122>(s); s += rorf<0x124>(s); s += rorf<0x128>(s);
      sq[r] = s;
    }
    // sTh packed writes + cols atomics
    {
      unsigned short h0s = f2bf(sval[0]);
      unsigned short h1s = f2bf(sval[1]);
      unsigned short h2s = f2bf(sval[2]);
      unsigned short h3s = f2bf(sval[3]);
      const int nb = lm * 264 + mbase + quad * 4;
      *(uint2*)(sTh + nb) = make_uint2(pk2(h0s, h1s), pk2(h2s, h3s));
      float sr = (bf2f(h0s) + bf2f(h1s)) + (bf2f(h2s) + bf2f(h3s));
      sr += __shfl_xor(sr, 16, 64);
      sr += __shfl_xor(sr, 32, 64);
      if (lane < 16) atomicAdd(colsF + lm, sr);
    }
    // den partial: node mbase+l (l<16): ssq from quad l>>2, slot l&3
    {
      int l = lane & 15, src = (l >> 2) << 4;
      float q0 = __shfl(sq[0], src, 64), q1 = __shfl(sq[1], src, 64);
      float q2 = __shfl(sq[2], src, 64), q3 = __shfl(sq[3], src, 64);
      float ssel = (l & 2) ? ((l & 1) ? q3 : q2) : ((l & 1) ? q1 : q0);
      float vden = (lane < 16) ? degf * ssel : 0.f;
      #pragma unroll
      for (int o = 32; o > 0; o >>= 1) vden += __shfl_xor(vden, o, 64);
      if (lane == 0) scrE[wv] = vden;
    }
  }
  __syncthreads();   // B5: sTh ready; colsF complete

  // ---- P5: tA = A@s -> taT bf16 (adj re-read from LDS, magic decode) ----
  {
    float cols = colsF[lm];
    f32x4 tacc = {0.f, 0.f, 0.f, 0.f};
    const char* arow = smem + (mbase + lm) * 132;
    #pragma unroll
    for (int ks = 0; ks < 8; ++ks) {
      unsigned d = *(const unsigned int*)(arow + ks * 16 + quad * 4);
      s16x8 af = dec8(d);
      const int v0 = ks * 32 + quad * 8;
      s16x8 bh = *(const s16x8*)(sTh + lm * 264 + v0);
      tacc = __builtin_amdgcn_mfma_f32_16x16x32_bf16(af, bh, tacc, 0, 0, 0);
    }
    float c16 = 16.f * cols;                            // offset-16 correction
    *(uint2*)(taT + lm * 264 + mbase + quad * 4) =
        make_uint2(pk2(f2bf(tacc[0] - c16), f2bf(tacc[1] - c16)),
                   pk2(f2bf(tacc[2] - c16), f2bf(tacc[3] - c16)));
  }
  __syncthreads();   // B6: adjacency dead

  // ---- P6: FG weights reg -> LDS (no global loads) + 4 MFMA reduction jobs ----
  rel2f[t] = fg_rel2;
  root2f[t] = fg_root2;
  lin2f[t] = fg_lin2;
  if (t < 320) lin3f[t] = fg_lin3;
  if (t < 32) brel2f[t] = fg_brel2;
  if (t < 32) blin2f[t] = fg_blin2;
  if (t < 10) blin3f[t] = fg_blin3;

  if (wv < 4) {
    const unsigned short* Ap = sTh;
    const unsigned short* Bp; float* dst; int W, ct = 0;
    switch (wv) {
      case 0: Bp = h1Th; dst = pbuf;  W = 32; ct = 0; break;
      case 1: Bp = h1Th; dst = pbuf;  W = 32; ct = 1; break;
      case 2: Bp = taT;  dst = oadjb; W = 16; break;
      default: Bp = sTh; dst = ssA;   W = 16; break;
    }
    const int cidx = ct * 16 + lm;
    const unsigned short* Bb = Bp + cidx * 264;
    f32x4 acc = {0.f, 0.f, 0.f, 0.f};
    #pragma unroll
    for (int ch = 0; ch < 8; ++ch) {
      s16x8 a = *(const s16x8*)(Ap + lm * 264 + ch * 32 + quad * 8);
      s16x8 bb = *(const s16x8*)(Bb + ch * 32 + quad * 8);
      acc = __builtin_amdgcn_mfma_f32_16x16x32_bf16(a, bb, acc, 0, 0, 0);
    }
    #pragma unroll
    for (int r = 0; r < 4; ++r) dst[(quad * 4 + r) * W + cidx] = acc[r];
  }
  __syncthreads();   // B7 — LAST barrier

  // ---- tail: wave0 = output chain (intra-wave), wave1 = loss chain ----
  if (wv == 0) {
    // degree vector of pooled adj (row sums excluding diag)
    if (lane < 16) {
      float rs = 0.f;
      #pragma unroll
      for (int j = 0; j < 16; ++j) if (j != lane) rs += oadjb[lane * 16 + j];
      ddb[lane] = sqrtf(rs) + 1e-15f;
    }
    // colsums of normalized adj (never materialize the matrix)
    if (lane < 16) {
      float s = 0.f;
      float dj = ddb[lane];
      #pragma unroll
      for (int k = 0; k < 16; ++k)
        if (k != lane) s += oadjb[k * 16 + lane] / (ddb[k] * dj);
      caf[lane] = s;
    }
    // ps = colsum(pbuf), qs = ca^T pbuf   (readout-sum commuted past conv2)
    if (lane < 32) {
      float ps = 0.f, qs = 0.f;
      #pragma unroll
      for (int j = 0; j < 16; ++j) {
        float pv = pbuf[j * 32 + lane];
        ps += pv;
        qs += caf[j] * pv;
      }
      psf[lane] = ps; qsf[lane] = qs;
    }
    // r = 16*brel2 + qs@Wrel2 + ps@Wroot2
    if (lane < 32) {
      float r = 16.f * brel2f[lane];
      #pragma unroll
      for (int m = 0; m < 32; ++m)
        r += qsf[m] * rel2f[m * 32 + lane] + psf[m] * root2f[m * 32 + lane];
      rb[lane] = r;
    }
    if (lane < 32) {
      float y = blin2f[lane];
      #pragma unroll
      for (int m = 0; m < 32; ++m) y += rb[m] * lin2f[m * 32 + lane];
      yb[lane] = fmaxf(y, 0.f);
    }
    if (lane < 10) {
      float lg = blin3f[lane];
      #pragma unroll
      for (int m = 0; m < 32; ++m) lg += yb[m] * lin3f[m * 10 + lane];
      lgb[lane] = lg;
    }
    if (lane == 0) {
      float mx = lgb[0];
      #pragma unroll
      for (int i = 1; i < 10; ++i) mx = fmaxf(mx, lgb[i]);
      float sum = 0.f;
      #pragma unroll
      for (int i = 0; i < 10; ++i) sum += __expf(lgb[i] - mx);
      lgb[10] = mx + __logf(sum);
    }
    if (lane < 10) {
      float val = lgb[lane] - lgb[10];
      if (BF) ((unsigned short*)P.out)[b * 10 + lane] = f2bf(val);
      else    P.out[b * 10 + lane] = val;
    }
  } else if (wv == 1) {
    float vfro = 0.f, vtr = 0.f;
    #pragma unroll
    for (int u = 0; u < 4; ++u) {
      int i = lane * 4 + u, k = i >> 4, j = i & 15;
      float ssv = ssA[i];
      vfro += ssv * ssv;
      if (k == j) vtr += ssv;
    }
    float vnum = (lane < 16) ? oadjb[lane * 17] : 0.f;
    float vden = (lane < 16) ? scrE[lane] : 0.f;
    #pragma unroll
    for (int o = 32; o > 0; o >>= 1) {
      vfro += __shfl_xor(vfro, o, 64);
      vtr  += __shfl_xor(vtr, o, 64);
      vnum += __shfl_xor(vnum, o, 64);
      vden += __shfl_xor(vden, o, 64);
    }
    if (lane == 0) {
      float ssn = sqrtf(vfro);
      float orth2 = 2.f - vtr / (2.f * ssn);
      atomicAdd(P.ws, -(vnum / vden) * (1.f / NB));
      atomicAdd(P.ws + 1, sqrtf(fmaxf(orth2, 0.f)) * (1.f / NB));
      // completion counter: last block writes the loss outputs (folds mincut_fin)
      __threadfence();
      unsigned old = atomicAdd((unsigned int*)(P.ws + 2), 1u);
      if (old == (unsigned)(NB - 1)) {
        float l0 = atomicAdd(P.ws, 0.f);      // coherent RMW reads
        float l1 = atomicAdd(P.ws + 1, 0.f);
        if (BF) {
          ((unsigned short*)P.out)[5120] = f2bf(l0);
          ((unsigned short*)P.out)[5121] = f2bf(l1);
        } else {
          P.out[5120] = l0;
          P.out[5121] = l1;
        }
      }
    }
  }
}

extern "C" void kernel_launch(void* const* d_in, const int* in_sizes, int n_in,
                              void* d_out, int out_size, void* d_ws, size_t ws_size,
                              hipStream_t stream) {
  (void)in_sizes; (void)n_in; (void)out_size; (void)ws_size;
  Params P;
  P.x    = d_in[0];
  P.ei   = d_in[1];
  P.wl1  = d_in[3];
  P.bl1  = d_in[4];
  P.wr1  = d_in[5];
  P.br1  = d_in[6];
  P.wro1 = d_in[7];
  P.wp   = d_in[8];
  P.bp   = d_in[9];
  P.wr2  = d_in[10];
  P.br2  = d_in[11];
  P.wro2 = d_in[12];
  P.wl2  = d_in[13];
  P.bl2  = d_in[14];
  P.wl3  = d_in[15];
  P.bl3  = d_in[16];
  P.out  = (float*)d_out;
  P.ws   = (float*)d_ws;

  hipMemsetAsync(d_ws, 0, 4 * sizeof(float), stream);
  hipFuncSetAttribute(reinterpret_cast<const void*>(mincut_main),
                      hipFuncAttributeMaxDynamicSharedMemorySize, SMEM_TOTAL);
  hipLaunchKernelGGL(mincut_main, dim3(NB), dim3(1024), SMEM_TOTAL, stream, P);
}